// Round 8
// baseline (304.190 us; speedup 1.0000x reference)
//
#include <hip/hip_runtime.h>
#include <hip/hip_fp16.h>
#include <math.h>

// GCN 2-layer forward on MI355X — round 8:
//  - k_fat gemm: explicit 1-ahead x-load prefetch + __launch_bounds__(256,4)
//  - k_wpack: dinv[s] quantized (q15) into csr top bits -> gathers lose one
//    random dependent load per edge
//  - 8-deep MLP unroll in both gather loops

#define BSH  9                 // bucket = dst >> 9 (512 nodes/bucket)
#define BCAP 12288             // max edges per bucket (mean 8163, ~45 sigma)

typedef _Float16 half8 __attribute__((ext_vector_type(8)));
typedef float floatx4 __attribute__((ext_vector_type(4)));

// -------- W1 -> fp16 B-fragment swizzle --------
static __global__ __launch_bounds__(256) void k_wfrag(const float* __restrict__ W1,
                                                      _Float16* __restrict__ w1f) {
    int t = threadIdx.x;
    for (int idx = t; idx < 2048; idx += 256) {
        int kb = idx >> 8;
        int nt = (idx >> 6) & 3;
        int l  = idx & 63;
        int k0 = kb * 32 + ((l >> 4) << 3);
        int nn = nt * 16 + (l & 15);
        half8 b;
        #pragma unroll
        for (int j = 0; j < 8; ++j) b[j] = (_Float16)W1[(k0 + j) * 64 + nn];
        *(half8*)(w1f + (size_t)idx * 8) = b;
    }
}

// -------- fat kernel: blocks [0,nScat) = edge bucketing, rest = MFMA gemm1 --------
static __global__ __launch_bounds__(256, 4) void k_fat(const float* __restrict__ x,
                                                       const _Float16* __restrict__ w1f,
                                                       _Float16* __restrict__ h1f,
                                                       const int* __restrict__ src,
                                                       const int* __restrict__ dst,
                                                       int* __restrict__ bkt_cnt,
                                                       int* __restrict__ epack,
                                                       int n, int e, int nScat) {
    __shared__ alignas(16) char smem[32768];
    int t = threadIdx.x;

    if ((int)blockIdx.x < nScat) {
        // ---- edge bucketing ----
        int*           sp    = (int*)smem;
        unsigned char* sbkt  = (unsigned char*)(smem + 16384);
        int*           cnt   = (int*)(smem + 20480);
        int*           loff  = (int*)(smem + 21504);
        int*           lcur  = (int*)(smem + 22528);
        int*           gbase = (int*)(smem + 23552);
        int*           sh    = (int*)(smem + 24576);
        int cb = blockIdx.x * 4096;
        int cc = min(4096, e - cb);

        cnt[t] = 0;
        __syncthreads();
        int ep[16]; unsigned char eb[16];
        int nv = 0;
        #pragma unroll
        for (int k = 0; k < 16; ++k) {
            int i = cb + k * 256 + t;
            if (i < e) {
                int s = src[i], d = dst[i];
                int b = d >> BSH;
                ep[nv] = ((d & 511) << 17) | s;
                eb[nv] = (unsigned char)b;
                atomicAdd(&cnt[b], 1);
                ++nv;
            }
        }
        __syncthreads();
        int v = cnt[t];
        sh[t] = v;
        __syncthreads();
        for (int o = 1; o < 256; o <<= 1) {
            int u = (t >= o) ? sh[t - o] : 0;
            __syncthreads();
            sh[t] += u;
            __syncthreads();
        }
        loff[t] = sh[t] - v;
        lcur[t] = sh[t] - v;
        if (v > 0) gbase[t] = t * BCAP + atomicAdd(&bkt_cnt[t], v);
        __syncthreads();
        for (int k = 0; k < nv; ++k) {
            int b = eb[k];
            int p = atomicAdd(&lcur[b], 1);
            sp[p] = ep[k];
            sbkt[p] = (unsigned char)b;
        }
        __syncthreads();
        for (int i = t; i < cc; i += 256) {
            int b = sbkt[i];
            epack[gbase[b] + (i - loff[b])] = sp[i];
        }
    } else {
        // ---- gemm1 on MFMA with 1-ahead load prefetch ----
        _Float16* Wl = (_Float16*)smem;
        {
            const float4* s = (const float4*)w1f;
            float4* d = (float4*)smem;
            #pragma unroll
            for (int i = 0; i < 8; ++i) d[t + i * 256] = s[t + i * 256];
        }
        __syncthreads();

        int l = t & 63;
        int w = t >> 6;
        int r0 = (blockIdx.x - nScat) * 128 + w * 32;
        int kq = (l >> 4) << 3;
        int ra0 = r0 + (l & 15);
        int ra1 = ra0 + 16;
        ra0 = ra0 < n ? ra0 : n - 1;
        ra1 = ra1 < n ? ra1 : n - 1;
        const float* p0 = x + (size_t)ra0 * 256 + kq;
        const float* p1 = x + (size_t)ra1 * 256 + kq;

        floatx4 acc[2][4];
        #pragma unroll
        for (int mt = 0; mt < 2; ++mt)
            #pragma unroll
            for (int nt = 0; nt < 4; ++nt)
                acc[mt][nt] = (floatx4){0.f, 0.f, 0.f, 0.f};

        float4 cu0 = *(const float4*)(p0);
        float4 cu1 = *(const float4*)(p0 + 4);
        float4 cv0 = *(const float4*)(p1);
        float4 cv1 = *(const float4*)(p1 + 4);

        #pragma unroll
        for (int kb = 0; kb < 8; ++kb) {
            float4 nu0, nu1, nv0, nv1;
            if (kb < 7) {
                nu0 = *(const float4*)(p0 + (kb + 1) * 32);
                nu1 = *(const float4*)(p0 + (kb + 1) * 32 + 4);
                nv0 = *(const float4*)(p1 + (kb + 1) * 32);
                nv1 = *(const float4*)(p1 + (kb + 1) * 32 + 4);
            }
            half8 a0, a1;
            a0[0] = (_Float16)cu0.x; a0[1] = (_Float16)cu0.y; a0[2] = (_Float16)cu0.z; a0[3] = (_Float16)cu0.w;
            a0[4] = (_Float16)cu1.x; a0[5] = (_Float16)cu1.y; a0[6] = (_Float16)cu1.z; a0[7] = (_Float16)cu1.w;
            a1[0] = (_Float16)cv0.x; a1[1] = (_Float16)cv0.y; a1[2] = (_Float16)cv0.z; a1[3] = (_Float16)cv0.w;
            a1[4] = (_Float16)cv1.x; a1[5] = (_Float16)cv1.y; a1[6] = (_Float16)cv1.z; a1[7] = (_Float16)cv1.w;
            #pragma unroll
            for (int nt = 0; nt < 4; ++nt) {
                half8 b = *(const half8*)(Wl + ((size_t)(kb * 4 + nt) * 64 + l) * 8);
                acc[0][nt] = __builtin_amdgcn_mfma_f32_16x16x32_f16(a0, b, acc[0][nt], 0, 0, 0);
                acc[1][nt] = __builtin_amdgcn_mfma_f32_16x16x32_f16(a1, b, acc[1][nt], 0, 0, 0);
            }
            cu0 = nu0; cu1 = nu1; cv0 = nv0; cv1 = nv1;
        }

        int quad = l >> 4;
        int col  = l & 15;
        #pragma unroll
        for (int mt = 0; mt < 2; ++mt) {
            #pragma unroll
            for (int r = 0; r < 4; ++r) {
                int rr = r0 + mt * 16 + quad * 4 + r;
                if (rr < n) {
                    _Float16* o = h1f + (size_t)rr * 64 + col;
                    #pragma unroll
                    for (int nt = 0; nt < 4; ++nt)
                        o[nt * 16] = (_Float16)acc[mt][nt][r];
                }
            }
        }
    }
}

// -------- per bucket: deg->dinv, LDS scan -> offs, fill csr_src --------
static __global__ __launch_bounds__(512) void k_bfinal(const int* __restrict__ bkt_cnt,
                                                       const int* __restrict__ epack,
                                                       float* __restrict__ dinv,
                                                       int* __restrict__ offs,
                                                       int* __restrict__ csr_src, int n) {
    __shared__ int cnt[512], sh[512], lcur[512];
    int t = threadIdx.x;
    int base = blockIdx.x << BSH;
    int e0 = blockIdx.x * BCAP;
    int e1 = e0 + bkt_cnt[blockIdx.x];
    cnt[t] = 0;
    __syncthreads();
    for (int i = e0 + t; i < e1; i += 512) atomicAdd(&cnt[epack[i] >> 17], 1);
    __syncthreads();
    int v = cnt[t];
    if (base + t < n) dinv[base + t] = 1.0f / sqrtf((float)(v + 1));
    sh[t] = v;
    __syncthreads();
    for (int o = 1; o < 512; o <<= 1) {
        int u = (t >= o) ? sh[t - o] : 0;
        __syncthreads();
        sh[t] += u;
        __syncthreads();
    }
    int incl = sh[t];
    if (base + t < n) offs[base + t] = e0 + incl;
    lcur[t] = e0 + incl - v;
    __syncthreads();
    for (int i = e0 + t; i < e1; i += 512) {
        int p = epack[i];
        int d = p >> 17;
        int pos = atomicAdd(&lcur[d], 1);
        csr_src[pos] = p & 0x1FFFF;
    }
}

// -------- pack q15 dinv[src] into csr top bits --------
static __global__ __launch_bounds__(512) void k_wpack(int* __restrict__ csr_src,
                                                      const float* __restrict__ dinv,
                                                      const int* __restrict__ bkt_cnt) {
    int b  = blockIdx.x;
    int e0 = b * BCAP;
    int e1 = e0 + bkt_cnt[b];
    for (int i = e0 + threadIdx.x; i < e1; i += 512) {
        int s = csr_src[i];
        int q = (int)(dinv[s] * 32767.0f + 0.5f);
        csr_src[i] = s | (q << 17);
    }
}

// -------- fused agg1 + gemm2 (packed weights, 8-deep MLP) --------
static __global__ __launch_bounds__(256) void k_agg1gemm2(const int* __restrict__ offs,
                                                          const int* __restrict__ csr_src,
                                                          const float* __restrict__ dinv,
                                                          const __half2* __restrict__ h1h,
                                                          const float* __restrict__ b1,
                                                          const float* __restrict__ W2,
                                                          __half* __restrict__ h2h, int n) {
    __shared__ float Wl[64 * 32];
    __shared__ float aggL[8][64];
    int t = threadIdx.x;
    *(float4*)(Wl + t * 4)        = *(const float4*)(W2 + t * 4);
    *(float4*)(Wl + t * 4 + 1024) = *(const float4*)(W2 + t * 4 + 1024);

    int li = t & 31;
    int ni = t >> 5;
    int node  = blockIdx.x * 8 + ni;
    int nodeC = node < n ? node : n - 1;
    int start = (nodeC & 511) ? offs[nodeC - 1] : (nodeC >> BSH) * BCAP;
    int end   = offs[nodeC];
    float dd  = dinv[nodeC];
    float2 hf = __half22float2(h1h[(size_t)nodeC * 32 + li]);
    float accx = dd * hf.x, accy = dd * hf.y;

    const float QS = 1.0f / 32767.0f;
    int j = start;
    for (; j + 7 < end; j += 8) {
        int pk[8];
        #pragma unroll
        for (int u = 0; u < 8; ++u) pk[u] = csr_src[j + u];
        float2 vv[8]; float wq[8];
        #pragma unroll
        for (int u = 0; u < 8; ++u) {
            int s = pk[u] & 0x1FFFF;
            wq[u] = (float)(((unsigned)pk[u]) >> 17) * QS;
            vv[u] = __half22float2(h1h[(size_t)s * 32 + li]);
        }
        #pragma unroll
        for (int u = 0; u < 8; ++u) { accx += wq[u] * vv[u].x; accy += wq[u] * vv[u].y; }
    }
    for (; j < end; ++j) {
        int p = csr_src[j];
        int s = p & 0x1FFFF;
        float w = (float)(((unsigned)p) >> 17) * QS;
        float2 v = __half22float2(h1h[(size_t)s * 32 + li]);
        accx += w * v.x;
        accy += w * v.y;
    }
    float2 bb = ((const float2*)b1)[li];
    aggL[ni][2 * li + 0] = fmaxf(dd * accx + bb.x, 0.f);
    aggL[ni][2 * li + 1] = fmaxf(dd * accy + bb.y, 0.f);
    __syncthreads();

    if (node < n) {
        float s = 0.f;
        #pragma unroll
        for (int k = 0; k < 64; ++k) s += aggL[ni][k] * Wl[k * 32 + li];
        h2h[(size_t)node * 32 + li] = __float2half(s);
    }
}

// -------- fused agg2 + final projection (packed weights, 8-deep MLP) --------
static __global__ __launch_bounds__(256) void k_gather2f(const int* __restrict__ offs,
                                                         const int* __restrict__ csr_src,
                                                         const float* __restrict__ dinv,
                                                         const __half2* __restrict__ h2h,
                                                         const float* __restrict__ b2,
                                                         const float* __restrict__ Wlin,
                                                         const float* __restrict__ blin,
                                                         float* __restrict__ out, int n) {
    int g    = blockIdx.x * 256 + threadIdx.x;
    int node = g >> 4;
    if (node >= n) return;
    int li = g & 15;
    int start = (node & 511) ? offs[node - 1] : (node >> BSH) * BCAP;
    int end   = offs[node];
    float dd  = dinv[node];
    float2 hf = __half22float2(h2h[(size_t)node * 16 + li]);
    float accx = dd * hf.x, accy = dd * hf.y;

    const float QS = 1.0f / 32767.0f;
    int j = start;
    for (; j + 7 < end; j += 8) {
        int pk[8];
        #pragma unroll
        for (int u = 0; u < 8; ++u) pk[u] = csr_src[j + u];
        float2 vv[8]; float wq[8];
        #pragma unroll
        for (int u = 0; u < 8; ++u) {
            int s = pk[u] & 0x1FFFF;
            wq[u] = (float)(((unsigned)pk[u]) >> 17) * QS;
            vv[u] = __half22float2(h2h[(size_t)s * 16 + li]);
        }
        #pragma unroll
        for (int u = 0; u < 8; ++u) { accx += wq[u] * vv[u].x; accy += wq[u] * vv[u].y; }
    }
    for (; j < end; ++j) {
        int p = csr_src[j];
        int s = p & 0x1FFFF;
        float w = (float)(((unsigned)p) >> 17) * QS;
        float2 v = __half22float2(h2h[(size_t)s * 16 + li]);
        accx += w * v.x;
        accy += w * v.y;
    }
    float2 bb = ((const float2*)b2)[li];
    float2 wl = ((const float2*)Wlin)[li];
    float val = fmaxf(dd * accx + bb.x, 0.f) * wl.x +
                fmaxf(dd * accy + bb.y, 0.f) * wl.y;
    #pragma unroll
    for (int m = 8; m >= 1; m >>= 1) val += __shfl_xor(val, m);
    if (li == 0) out[node] = val + blin[0];
}

extern "C" void kernel_launch(void* const* d_in, const int* in_sizes, int n_in,
                              void* d_out, int out_size, void* d_ws, size_t ws_size,
                              hipStream_t stream) {
    const float* x    = (const float*)d_in[0];
    const int*   ei   = (const int*)d_in[1];
    const float* W1   = (const float*)d_in[2];
    const float* b1   = (const float*)d_in[3];
    const float* W2   = (const float*)d_in[4];
    const float* b2   = (const float*)d_in[5];
    const float* Wlin = (const float*)d_in[6];
    const float* blin = (const float*)d_in[7];
    float* out = (float*)d_out;

    const int n = in_sizes[0] / 256;   // 100000
    const int e = in_sizes[1] / 2;     // 1600000
    const int* src = ei;
    const int* dst = ei + e;
    const int nbkt  = (n + (1 << BSH) - 1) >> BSH;   // 196
    const int nScat = (e + 4095) / 4096;             // 391
    const int nGemm = (n + 127) / 128;               // 782

    char* wp = (char*)d_ws;
    __half2*  h1h = (__half2*)wp;
    _Float16* h1f = (_Float16*)wp;    wp += (size_t)n * 32 * 4;
    __half*   h2h = (__half*)wp;      wp += (size_t)n * 32 * 2;
    float*    dinv = (float*)wp;      wp += (size_t)n * 4;
    int*      offs = (int*)wp;        wp += (size_t)n * 4;
    int*      csr_src = (int*)wp;     wp += (size_t)nbkt * BCAP * 4;
    int*      epack = (int*)wp;       wp += (size_t)nbkt * BCAP * 4;
    int*      bkt_cnt = (int*)wp;     wp += 256 * 4;
    _Float16* w1f = (_Float16*)wp;    // 32 KB

    dim3 B(256);
    hipMemsetAsync(bkt_cnt, 0, 256 * 4, stream);
    k_wfrag <<<1, B, 0, stream>>>(W1, w1f);
    k_fat   <<<nScat + nGemm, B, 0, stream>>>(x, w1f, h1f, src, dst, bkt_cnt, epack, n, e, nScat);
    k_bfinal<<<nbkt, 512, 0, stream>>>(bkt_cnt, epack, dinv, offs, csr_src, n);
    k_wpack <<<nbkt, 512, 0, stream>>>(csr_src, dinv, bkt_cnt);
    k_agg1gemm2<<<(n + 7) / 8, B, 0, stream>>>(offs, csr_src, dinv, h1h, b1, W2, h2h, n);
    k_gather2f <<<(n * 16 + 255) / 256, B, 0, stream>>>(offs, csr_src, dinv, (const __half2*)h2h,
                                                        b2, Wlin, blin, out, n);
}

// Round 9
// 291.294 us; speedup vs baseline: 1.0443x; 1.0443x over previous
//
#include <hip/hip_runtime.h>
#include <hip/hip_fp16.h>
#include <math.h>

// GCN 2-layer forward on MI355X — round 9:
//  - k_fat gemm: x-tile staged through LDS (coalesced float4 -> fp16),
//    MFMA A-fragments from LDS (16B-aligned, 2-way banks) — kills the
//    64-scattered-16B-requests-per-instr pattern of rounds 6-8
//  - agg1gemm2: 16 lanes/node x 4 feats (2x node MLP per wave)
//  - gather2f: 8 lanes/node x 4 feats
//  - bkt_cnt zeroing folded into k_wfrag

#define BSH  9                 // bucket = dst >> 9 (512 nodes/bucket)
#define BCAP 12288             // max edges per bucket (mean 8163, ~45 sigma)

typedef _Float16 half8 __attribute__((ext_vector_type(8)));
typedef _Float16 half4 __attribute__((ext_vector_type(4)));
typedef float floatx4 __attribute__((ext_vector_type(4)));

#define XT_STRIDE 40           // halfs per x-tile row: 80 B, 16B-aligned, 2-way banks

// -------- W1 -> fp16 B-fragment swizzle + bkt_cnt zero --------
static __global__ __launch_bounds__(256) void k_wfrag(const float* __restrict__ W1,
                                                      _Float16* __restrict__ w1f,
                                                      int* __restrict__ bkt_cnt) {
    int t = threadIdx.x;
    bkt_cnt[t] = 0;
    for (int idx = t; idx < 2048; idx += 256) {
        int kb = idx >> 8;
        int nt = (idx >> 6) & 3;
        int l  = idx & 63;
        int k0 = kb * 32 + ((l >> 4) << 3);
        int nn = nt * 16 + (l & 15);
        half8 b;
        #pragma unroll
        for (int j = 0; j < 8; ++j) b[j] = (_Float16)W1[(k0 + j) * 64 + nn];
        *(half8*)(w1f + (size_t)idx * 8) = b;
    }
}

// -------- fat kernel: blocks [0,nScat) = edge bucketing, rest = MFMA gemm1 --------
static __global__ __launch_bounds__(256) void k_fat(const float* __restrict__ x,
                                                    const _Float16* __restrict__ w1f,
                                                    _Float16* __restrict__ h1f,
                                                    const int* __restrict__ src,
                                                    const int* __restrict__ dst,
                                                    int* __restrict__ bkt_cnt,
                                                    int* __restrict__ epack,
                                                    int n, int e, int nScat) {
    __shared__ alignas(16) char smem[32768 + 128 * XT_STRIDE * 2];
    int t = threadIdx.x;

    if ((int)blockIdx.x < nScat) {
        // ---- edge bucketing (unchanged) ----
        int*           sp    = (int*)smem;
        unsigned char* sbkt  = (unsigned char*)(smem + 16384);
        int*           cnt   = (int*)(smem + 20480);
        int*           loff  = (int*)(smem + 21504);
        int*           lcur  = (int*)(smem + 22528);
        int*           gbase = (int*)(smem + 23552);
        int*           sh    = (int*)(smem + 24576);
        int cb = blockIdx.x * 4096;
        int cc = min(4096, e - cb);

        cnt[t] = 0;
        __syncthreads();
        int ep[16]; unsigned char eb[16];
        int nv = 0;
        #pragma unroll
        for (int k = 0; k < 16; ++k) {
            int i = cb + k * 256 + t;
            if (i < e) {
                int s = src[i], d = dst[i];
                int b = d >> BSH;
                ep[nv] = ((d & 511) << 17) | s;
                eb[nv] = (unsigned char)b;
                atomicAdd(&cnt[b], 1);
                ++nv;
            }
        }
        __syncthreads();
        int v = cnt[t];
        sh[t] = v;
        __syncthreads();
        for (int o = 1; o < 256; o <<= 1) {
            int u = (t >= o) ? sh[t - o] : 0;
            __syncthreads();
            sh[t] += u;
            __syncthreads();
        }
        loff[t] = sh[t] - v;
        lcur[t] = sh[t] - v;
        if (v > 0) gbase[t] = t * BCAP + atomicAdd(&bkt_cnt[t], v);
        __syncthreads();
        for (int k = 0; k < nv; ++k) {
            int b = eb[k];
            int p = atomicAdd(&lcur[b], 1);
            sp[p] = ep[k];
            sbkt[p] = (unsigned char)b;
        }
        __syncthreads();
        for (int i = t; i < cc; i += 256) {
            int b = sbkt[i];
            epack[gbase[b] + (i - loff[b])] = sp[i];
        }
    } else {
        // ---- gemm1 on MFMA, x staged through LDS ----
        _Float16* Wl = (_Float16*)smem;                    // 32 KB B-fragments
        _Float16* xt = (_Float16*)(smem + 32768);          // 128 x XT_STRIDE fp16
        {
            const float4* s = (const float4*)w1f;
            float4* d = (float4*)smem;
            #pragma unroll
            for (int i = 0; i < 8; ++i) d[t + i * 256] = s[t + i * 256];
        }

        int l = t & 63;
        int w = t >> 6;
        int r0 = (blockIdx.x - nScat) * 128;
        int kq = (l >> 4) << 3;
        int lrow0 = w * 32 + (l & 15);
        int lrow1 = lrow0 + 16;

        floatx4 acc[2][4];
        #pragma unroll
        for (int mt = 0; mt < 2; ++mt)
            #pragma unroll
            for (int nt = 0; nt < 4; ++nt)
                acc[mt][nt] = (floatx4){0.f, 0.f, 0.f, 0.f};

        #pragma unroll
        for (int kb = 0; kb < 8; ++kb) {
            __syncthreads();   // previous iteration's fragment reads (and W stage) done
            #pragma unroll
            for (int i = 0; i < 4; ++i) {
                int f   = t + i * 256;        // 0..1023 over [row][c4]
                int row = f >> 3;
                int c4  = f & 7;
                int gr  = r0 + row;
                gr = gr < n ? gr : n - 1;
                float4 v = *(const float4*)(x + (size_t)gr * 256 + kb * 32 + c4 * 4);
                half4 h;
                h[0] = (_Float16)v.x; h[1] = (_Float16)v.y;
                h[2] = (_Float16)v.z; h[3] = (_Float16)v.w;
                *(half4*)(xt + row * XT_STRIDE + c4 * 4) = h;
            }
            __syncthreads();

            half8 a0 = *(const half8*)(xt + lrow0 * XT_STRIDE + kq);
            half8 a1 = *(const half8*)(xt + lrow1 * XT_STRIDE + kq);
            #pragma unroll
            for (int nt = 0; nt < 4; ++nt) {
                half8 b = *(const half8*)(Wl + ((size_t)(kb * 4 + nt) * 64 + l) * 8);
                acc[0][nt] = __builtin_amdgcn_mfma_f32_16x16x32_f16(a0, b, acc[0][nt], 0, 0, 0);
                acc[1][nt] = __builtin_amdgcn_mfma_f32_16x16x32_f16(a1, b, acc[1][nt], 0, 0, 0);
            }
        }

        int quad = l >> 4;
        int col  = l & 15;
        int rb0  = r0 + w * 32;
        #pragma unroll
        for (int mt = 0; mt < 2; ++mt) {
            #pragma unroll
            for (int r = 0; r < 4; ++r) {
                int rr = rb0 + mt * 16 + quad * 4 + r;
                if (rr < n) {
                    _Float16* o = h1f + (size_t)rr * 64 + col;
                    #pragma unroll
                    for (int nt = 0; nt < 4; ++nt)
                        o[nt * 16] = (_Float16)acc[mt][nt][r];
                }
            }
        }
    }
}

// -------- per bucket: deg->dinv, LDS scan -> offs, fill csr_src --------
static __global__ __launch_bounds__(512) void k_bfinal(const int* __restrict__ bkt_cnt,
                                                       const int* __restrict__ epack,
                                                       float* __restrict__ dinv,
                                                       int* __restrict__ offs,
                                                       int* __restrict__ csr_src, int n) {
    __shared__ int cnt[512], sh[512], lcur[512];
    int t = threadIdx.x;
    int base = blockIdx.x << BSH;
    int e0 = blockIdx.x * BCAP;
    int e1 = e0 + bkt_cnt[blockIdx.x];
    cnt[t] = 0;
    __syncthreads();
    for (int i = e0 + t; i < e1; i += 512) atomicAdd(&cnt[epack[i] >> 17], 1);
    __syncthreads();
    int v = cnt[t];
    if (base + t < n) dinv[base + t] = 1.0f / sqrtf((float)(v + 1));
    sh[t] = v;
    __syncthreads();
    for (int o = 1; o < 512; o <<= 1) {
        int u = (t >= o) ? sh[t - o] : 0;
        __syncthreads();
        sh[t] += u;
        __syncthreads();
    }
    int incl = sh[t];
    if (base + t < n) offs[base + t] = e0 + incl;
    lcur[t] = e0 + incl - v;
    __syncthreads();
    for (int i = e0 + t; i < e1; i += 512) {
        int p = epack[i];
        int d = p >> 17;
        int pos = atomicAdd(&lcur[d], 1);
        csr_src[pos] = p & 0x1FFFF;
    }
}

// -------- pack q15 dinv[src] into csr top bits --------
static __global__ __launch_bounds__(512) void k_wpack(int* __restrict__ csr_src,
                                                      const float* __restrict__ dinv,
                                                      const int* __restrict__ bkt_cnt) {
    int b  = blockIdx.x;
    int e0 = b * BCAP;
    int e1 = e0 + bkt_cnt[b];
    for (int i = e0 + threadIdx.x; i < e1; i += 512) {
        int s = csr_src[i];
        int q = (int)(dinv[s] * 32767.0f + 0.5f);
        csr_src[i] = s | (q << 17);
    }
}

// -------- fused agg1 + gemm2: 16 lanes/node x 4 feats --------
static __global__ __launch_bounds__(256) void k_agg1gemm2(const int* __restrict__ offs,
                                                          const int* __restrict__ csr_src,
                                                          const float* __restrict__ dinv,
                                                          const uint2* __restrict__ h1q,
                                                          const float* __restrict__ b1,
                                                          const float* __restrict__ W2,
                                                          __half2* __restrict__ h2h, int n) {
    __shared__ float Wl[64 * 32];     // 8 KB
    __shared__ float aggL[16][64];    // 4 KB
    int t = threadIdx.x;
    *(float4*)(Wl + t * 4)        = *(const float4*)(W2 + t * 4);
    *(float4*)(Wl + t * 4 + 1024) = *(const float4*)(W2 + t * 4 + 1024);

    int li = t & 15;
    int ni = t >> 4;
    int node  = blockIdx.x * 16 + ni;
    int nodeC = node < n ? node : n - 1;
    int start = (nodeC & 511) ? offs[nodeC - 1] : (nodeC >> BSH) * BCAP;
    int end   = offs[nodeC];
    float dd  = dinv[nodeC];

    uint2 su = h1q[(size_t)nodeC * 16 + li];
    float2 s01 = __half22float2(*(const __half2*)&su.x);
    float2 s23 = __half22float2(*(const __half2*)&su.y);
    float a0 = dd * s01.x, a1 = dd * s01.y, a2 = dd * s23.x, a3 = dd * s23.y;

    const float QS = 1.0f / 32767.0f;
    int j = start;
    for (; j + 7 < end; j += 8) {
        int pk[8];
        #pragma unroll
        for (int u = 0; u < 8; ++u) pk[u] = csr_src[j + u];
        uint2 vv[8]; float wq[8];
        #pragma unroll
        for (int u = 0; u < 8; ++u) {
            int s = pk[u] & 0x1FFFF;
            wq[u] = (float)(((unsigned)pk[u]) >> 17) * QS;
            vv[u] = h1q[(size_t)s * 16 + li];
        }
        #pragma unroll
        for (int u = 0; u < 8; ++u) {
            float2 v01 = __half22float2(*(const __half2*)&vv[u].x);
            float2 v23 = __half22float2(*(const __half2*)&vv[u].y);
            a0 += wq[u] * v01.x; a1 += wq[u] * v01.y;
            a2 += wq[u] * v23.x; a3 += wq[u] * v23.y;
        }
    }
    for (; j < end; ++j) {
        int p = csr_src[j];
        int s = p & 0x1FFFF;
        float wv = (float)(((unsigned)p) >> 17) * QS;
        uint2 v = h1q[(size_t)s * 16 + li];
        float2 v01 = __half22float2(*(const __half2*)&v.x);
        float2 v23 = __half22float2(*(const __half2*)&v.y);
        a0 += wv * v01.x; a1 += wv * v01.y;
        a2 += wv * v23.x; a3 += wv * v23.y;
    }
    float4 bb = *(const float4*)(b1 + li * 4);
    aggL[ni][li * 4 + 0] = fmaxf(dd * a0 + bb.x, 0.f);
    aggL[ni][li * 4 + 1] = fmaxf(dd * a1 + bb.y, 0.f);
    aggL[ni][li * 4 + 2] = fmaxf(dd * a2 + bb.z, 0.f);
    aggL[ni][li * 4 + 3] = fmaxf(dd * a3 + bb.w, 0.f);
    __syncthreads();

    if (node < n) {
        float s0 = 0.f, s1 = 0.f;
        #pragma unroll
        for (int k = 0; k < 64; ++k) {
            float a = aggL[ni][k];
            float2 wv = *(const float2*)(Wl + k * 32 + li * 2);
            s0 += a * wv.x;
            s1 += a * wv.y;
        }
        h2h[(size_t)node * 16 + li] = __float22half2_rn(make_float2(s0, s1));
    }
}

// -------- fused agg2 + final projection: 8 lanes/node x 4 feats --------
static __global__ __launch_bounds__(256) void k_gather2f(const int* __restrict__ offs,
                                                         const int* __restrict__ csr_src,
                                                         const float* __restrict__ dinv,
                                                         const uint2* __restrict__ h2q,
                                                         const float* __restrict__ b2,
                                                         const float* __restrict__ Wlin,
                                                         const float* __restrict__ blin,
                                                         float* __restrict__ out, int n) {
    int g    = blockIdx.x * 256 + threadIdx.x;
    int node = g >> 3;
    if (node >= n) return;
    int li = g & 7;
    int start = (node & 511) ? offs[node - 1] : (node >> BSH) * BCAP;
    int end   = offs[node];
    float dd  = dinv[node];

    uint2 su = h2q[(size_t)node * 8 + li];
    float2 s01 = __half22float2(*(const __half2*)&su.x);
    float2 s23 = __half22float2(*(const __half2*)&su.y);
    float a0 = dd * s01.x, a1 = dd * s01.y, a2 = dd * s23.x, a3 = dd * s23.y;

    const float QS = 1.0f / 32767.0f;
    int j = start;
    for (; j + 7 < end; j += 8) {
        int pk[8];
        #pragma unroll
        for (int u = 0; u < 8; ++u) pk[u] = csr_src[j + u];
        uint2 vv[8]; float wq[8];
        #pragma unroll
        for (int u = 0; u < 8; ++u) {
            int s = pk[u] & 0x1FFFF;
            wq[u] = (float)(((unsigned)pk[u]) >> 17) * QS;
            vv[u] = h2q[(size_t)s * 8 + li];
        }
        #pragma unroll
        for (int u = 0; u < 8; ++u) {
            float2 v01 = __half22float2(*(const __half2*)&vv[u].x);
            float2 v23 = __half22float2(*(const __half2*)&vv[u].y);
            a0 += wq[u] * v01.x; a1 += wq[u] * v01.y;
            a2 += wq[u] * v23.x; a3 += wq[u] * v23.y;
        }
    }
    for (; j < end; ++j) {
        int p = csr_src[j];
        int s = p & 0x1FFFF;
        float wv = (float)(((unsigned)p) >> 17) * QS;
        uint2 v = h2q[(size_t)s * 8 + li];
        float2 v01 = __half22float2(*(const __half2*)&v.x);
        float2 v23 = __half22float2(*(const __half2*)&v.y);
        a0 += wv * v01.x; a1 += wv * v01.y;
        a2 += wv * v23.x; a3 += wv * v23.y;
    }
    float4 bb = *(const float4*)(b2 + li * 4);
    float4 wl = *(const float4*)(Wlin + li * 4);
    float val = fmaxf(dd * a0 + bb.x, 0.f) * wl.x +
                fmaxf(dd * a1 + bb.y, 0.f) * wl.y +
                fmaxf(dd * a2 + bb.z, 0.f) * wl.z +
                fmaxf(dd * a3 + bb.w, 0.f) * wl.w;
    val += __shfl_xor(val, 4);
    val += __shfl_xor(val, 2);
    val += __shfl_xor(val, 1);
    if (li == 0) out[node] = val + blin[0];
}

extern "C" void kernel_launch(void* const* d_in, const int* in_sizes, int n_in,
                              void* d_out, int out_size, void* d_ws, size_t ws_size,
                              hipStream_t stream) {
    const float* x    = (const float*)d_in[0];
    const int*   ei   = (const int*)d_in[1];
    const float* W1   = (const float*)d_in[2];
    const float* b1   = (const float*)d_in[3];
    const float* W2   = (const float*)d_in[4];
    const float* b2   = (const float*)d_in[5];
    const float* Wlin = (const float*)d_in[6];
    const float* blin = (const float*)d_in[7];
    float* out = (float*)d_out;

    const int n = in_sizes[0] / 256;   // 100000
    const int e = in_sizes[1] / 2;     // 1600000
    const int* src = ei;
    const int* dst = ei + e;
    const int nbkt  = (n + (1 << BSH) - 1) >> BSH;   // 196
    const int nScat = (e + 4095) / 4096;             // 391
    const int nGemm = (n + 127) / 128;               // 782

    char* wp = (char*)d_ws;
    _Float16* h1f = (_Float16*)wp;
    uint2*    h1q = (uint2*)wp;       wp += (size_t)n * 32 * 4;
    __half2*  h2h = (__half2*)wp;
    uint2*    h2q = (uint2*)wp;       wp += (size_t)n * 32 * 2;
    float*    dinv = (float*)wp;      wp += (size_t)n * 4;
    int*      offs = (int*)wp;        wp += (size_t)n * 4;
    int*      csr_src = (int*)wp;     wp += (size_t)nbkt * BCAP * 4;
    int*      epack = (int*)wp;       wp += (size_t)nbkt * BCAP * 4;
    int*      bkt_cnt = (int*)wp;     wp += 256 * 4;
    _Float16* w1f = (_Float16*)wp;    // 32 KB

    dim3 B(256);
    k_wfrag <<<1, B, 0, stream>>>(W1, w1f, bkt_cnt);
    k_fat   <<<nScat + nGemm, B, 0, stream>>>(x, w1f, h1f, src, dst, bkt_cnt, epack, n, e, nScat);
    k_bfinal<<<nbkt, 512, 0, stream>>>(bkt_cnt, epack, dinv, offs, csr_src, n);
    k_wpack <<<nbkt, 512, 0, stream>>>(csr_src, dinv, bkt_cnt);
    k_agg1gemm2<<<(n + 15) / 16, B, 0, stream>>>(offs, csr_src, dinv, h1q, b1, W2, h2h, n);
    k_gather2f <<<(n * 8 + 255) / 256, B, 0, stream>>>(offs, csr_src, dinv, h2q,
                                                       b2, Wlin, blin, out, n);
}